// Round 21
// baseline (547.851 us; speedup 1.0000x reference)
//
#include <hip/hip_runtime.h>
#include <stdint.h>

typedef unsigned long long u64;
typedef unsigned int u32;

#define NVERT 300000
#define NTET  1200000
#define NE    (NTET*6)              // 7,200,000 edges
#define TILE  2048
#define NTILES ((NE + TILE - 1)/TILE)   // 3516
#define IDXBITS 23
#define IDXMASK ((1u<<IDXBITS)-1)
#define CODESHIFT 24                // key = code<<24 | cross<<23 | idx ; code = e0<<19 | e1
#define NBUCKS 4688                 // fine bucket = key>>49 = e0>>6
#define BUCKSHIFT 49
#define NCOARSE 74                  // coarse bucket = key>>55 = e0>>12 (64 fine per coarse)
#define COARSESHIFT 55

// pack geometry
#define PK_GRID 512

// pass-1a geometry (register-held keys, 220 blocks)
#define P1_TPB  1024
#define P1_KPT  32
#define P1_KEYS (P1_TPB*P1_KPT)     // 32768
#define P1_GRID ((NE + P1_KEYS - 1)/P1_KEYS)   // 220

// pass-1b geometry
#define FS_SUB 8
#define FS_CH  32768

// mapping-scatter buckets (faces mapping)
#define BSHIFT 16
#define BSZ    65536
#define NBUCK  110
#define BPB    8
#define STAGECAP 1216               // TILE/2 mean + 8 sigma

// output layout (float32 elements)
#define VERTS_OFF 0
#define FACES_OFF 21600000
#define NUMT_OFF  28800000
#define CROSS_OFF 30000000
#define CODES_ELEM 14000000         // codes at bytes 56MB..86.4MB of d_out

__constant__ int c_ea[6] = {0,0,0,1,1,2};
__constant__ int c_eb[6] = {1,2,3,2,3,3};
__constant__ int c_numtri[16] = {0,1,1,2,1,2,2,1,1,2,2,1,2,1,1,0};
__constant__ int c_tritab[16][6] = {
 {-1,-1,-1,-1,-1,-1},{1,0,2,-1,-1,-1},{4,0,3,-1,-1,-1},{1,4,2,1,3,4},
 {3,1,5,-1,-1,-1},{2,3,0,2,5,3},{1,4,0,1,5,4},{4,2,5,-1,-1,-1},
 {4,5,2,-1,-1,-1},{4,1,0,4,5,1},{3,2,0,3,5,2},{1,3,5,-1,-1,-1},
 {4,1,2,4,3,1},{3,0,4,-1,-1,-1},{2,0,1,-1,-1,-1},{-1,-1,-1,-1,-1,-1}};

__device__ __forceinline__ int sw(int j){ return j ^ ((j >> 4) & 15); }

// grid-stride pack: 6 keys (LDS-staged coalesced) + occ nibble + per-block NON-ATOMIC hist row
__global__ __launch_bounds__(256) void k_pack(const int* __restrict__ tet, const float* __restrict__ sdf,
                       u64* __restrict__ dst, float* __restrict__ occF, u32* __restrict__ histBlk){
  __shared__ u32 h[NBUCKS];   // 18.75KB
  __shared__ u64 lk[256*6];   // 12KB key staging
  int tid = threadIdx.x;
  for (int r=tid; r<NBUCKS; r+=256) h[r]=0;
  __syncthreads();
  for (int t0 = blockIdx.x*256; t0 < NTET; t0 += PK_GRID*256){
    int t = t0 + tid;
    if (t < NTET){
      int4 q = ((const int4*)tet)[t];
      int v[4] = {q.x, q.y, q.z, q.w};
      u32 o[4];
      int occ = 0;
      #pragma unroll
      for (int j=0;j<4;j++){ o[j] = sdf[v[j]] > 0.f ? 1u : 0u; occ |= (int)o[j] << j; }
      occF[t] = (float)occ;
      u64 base = (u64)t*6;
      #pragma unroll
      for (int k=0;k<6;k++){
        int a = v[c_ea[k]], b = v[c_eb[k]];
        u64 cross = (o[c_ea[k]] != o[c_eb[k]]) ? 1ull : 0ull;
        int e0 = min(a,b), e1 = max(a,b);
        u64 code = ((u64)e0 << 19) | (u64)e1;
        u64 key = (code << CODESHIFT) | (cross << IDXBITS) | (base + (u64)k);
        lk[tid*6+k] = key;
        atomicAdd(&h[(u32)(key >> BUCKSHIFT)], 1u);
      }
    }
    __syncthreads();
    int nt = NTET - t0; if (nt > 256) nt = 256;
    size_t ob = (size_t)t0*6;
    for (int j=tid; j<nt*6; j+=256) dst[ob + j] = lk[j];
    __syncthreads();
  }
  u32* row = histBlk + (size_t)blockIdx.x * NBUCKS;
  for (int r=tid; r<NBUCKS; r+=256) row[r] = h[r];
}

// sum the 512 per-block hist rows (coalesced)
__global__ void k_reduce_hist(const u32* __restrict__ histBlk, u32* __restrict__ hist){
  int b = blockIdx.x*256 + threadIdx.x;
  if (b >= NBUCKS) return;
  u32 s = 0;
  for (int r=0;r<PK_GRID;r++) s += histBlk[(size_t)r*NBUCKS + b];
  hist[b] = s;
}

__global__ void k_psd(const float* __restrict__ pos, const float* __restrict__ sdf,
                      float4* __restrict__ psd){
  int v = blockIdx.x*blockDim.x + threadIdx.x;
  if (v < NVERT) psd[v] = make_float4(pos[3*v], pos[3*v+1], pos[3*v+2], sdf[v]);
}

// exclusive scan over fine buckets; writes boff, fine cursors AND coarse cursors
__global__ __launch_bounds__(1024) void k_scan_buckets(const u32* __restrict__ hist,
     u32* __restrict__ boff, u32* __restrict__ gcur, u32* __restrict__ ccur){
  __shared__ u32 s[1024];
  int tid = threadIdx.x;
  u32 carry = 0;
  for (int start=0; start<NBUCKS; start+=1024){
    int idx = start + tid;
    u32 x = (idx < NBUCKS) ? hist[idx] : 0;
    s[tid] = x; __syncthreads();
    for (int off=1; off<1024; off<<=1){
      u32 t = (tid >= off) ? s[tid-off] : 0;
      __syncthreads();
      s[tid] += t;
      __syncthreads();
    }
    u32 excl = carry + s[tid] - x;
    if (idx < NBUCKS){
      boff[idx] = excl; gcur[idx] = excl;
      if ((idx & 63) == 0) ccur[idx >> 6] = excl;
    }
    carry += s[1023];
    __syncthreads();
  }
}

// pass 1a: coarse partition (74 buckets). 32768 keys/block; runs ~443 keys -> coalesced
__global__ __launch_bounds__(P1_TPB) void k_coarse_scatter(const u64* __restrict__ src,
     u64* __restrict__ dst, u32* __restrict__ ccur){
  __shared__ u32 h[NCOARSE];
  int tid = threadIdx.x;
  if (tid < NCOARSE) h[tid]=0;
  __syncthreads();
  size_t gi = (size_t)blockIdx.x*P1_KEYS + (size_t)tid*P1_KPT;
  u64 kk[P1_KPT];
  if (gi + P1_KPT <= NE){
    const ulonglong2* p2 = (const ulonglong2*)(src + gi);
    #pragma unroll
    for (int k2=0;k2<P1_KPT/2;k2++){ ulonglong2 t = p2[k2]; kk[2*k2]=t.x; kk[2*k2+1]=t.y; }
  } else {
    #pragma unroll
    for (int k=0;k<P1_KPT;k++) kk[k] = (gi+k < NE) ? src[gi+k] : ~0ull;
  }
  #pragma unroll
  for (int k=0;k<P1_KPT;k++){
    if (gi+k < NE) atomicAdd(&h[(u32)(kk[k] >> COARSESHIFT)], 1u);
  }
  __syncthreads();
  if (tid < NCOARSE){
    u32 c = h[tid];
    h[tid] = c ? atomicAdd(&ccur[tid], c) : 0u;
  }
  __syncthreads();
  #pragma unroll
  for (int k=0;k<P1_KPT;k++){
    if (gi+k < NE){
      u32 b = (u32)(kk[k] >> COARSESHIFT);
      u32 p = atomicAdd(&h[b], 1u);
      dst[p] = kk[k];
    }
  }
}

// pass 1b: fine partition within each coarse region. grid = NCOARSE*FS_SUB.
__global__ __launch_bounds__(P1_TPB) void k_fine_scatter(const u64* __restrict__ src,
     u64* __restrict__ dst, const u32* __restrict__ boff, u32* __restrict__ gcur){
  __shared__ u32 h[64];
  __shared__ u32 rb[64];
  int c = blockIdx.x >> 3, sub = blockIdx.x & (FS_SUB-1);
  int tid = threadIdx.x;
  u32 startc = boff[c*64];
  u32 endc = (c == NCOARSE-1) ? (u32)NE : boff[(c+1)*64];
  u32 size = endc - startc;
  u32 shareLen = (size + FS_SUB - 1) / FS_SUB;
  u32 s0 = startc + sub*shareLen;
  u32 s1 = s0 + shareLen; if (s1 > endc) s1 = endc;
  if (s0 >= s1) return;
  for (u32 base = s0; base < s1; base += FS_CH){
    u32 lim = base + FS_CH; if (lim > s1) lim = s1;
    if (tid < 64) h[tid] = 0;
    __syncthreads();
    for (u32 i = base + tid; i < lim; i += P1_TPB)
      atomicAdd(&h[(u32)(src[i] >> BUCKSHIFT) & 63u], 1u);
    __syncthreads();
    if (tid < 64){
      u32 cc = h[tid];
      rb[tid] = cc ? atomicAdd(&gcur[c*64 + tid], cc) : 0u;
      h[tid] = 0;
    }
    __syncthreads();
    for (u32 i = base + tid; i < lim; i += P1_TPB){
      u64 v = src[i];
      u32 f = (u32)(v >> BUCKSHIFT) & 63u;
      u32 p = rb[f] + atomicAdd(&h[f], 1u);
      dst[p] = v;
    }
    __syncthreads();
  }
}

// pass 2: full in-LDS sort of one bucket (IN-PLACE). Size-classed NK in {4,8,12,16}.
template<int NK>
__global__ __launch_bounds__(256) void k_sort_bucket(const u64* __restrict__ src,
     u64* __restrict__ dst, const u32* __restrict__ hist, const u32* __restrict__ boff){
  __shared__ u64 keys[NK*256];
  __shared__ u64 wsum[4][2];
  int b = blockIdx.x, tid = threadIdx.x;
  u32 n = hist[b];
  if (n == 0) return;
  if (NK == 4  && n > 1024) return;
  if (NK == 8  && (n <= 1024 || n > 2048)) return;
  if (NK == 12 && (n <= 2048 || n > 3072)) return;
  if (NK == 16 && n <= 3072) return;
  u32 base = boff[b];
  #pragma unroll
  for (int k=0;k<NK;k++){
    int j = k*256 + tid;
    keys[sw(j)] = (j < (int)n) ? src[base + j] : ~0ull;
  }
  __syncthreads();
  int mywave = tid >> 6;
  #pragma unroll 1
  for (int q=0;q<9;q++){
    int sh = 24 + 3*q;
    u64 myk[NK];
    u64 vpack = 0;
    u64 c0 = 0, c1 = 0;
    #pragma unroll
    for (int k=0;k<NK;k++){
      myk[k] = keys[sw(tid*NK+k)];
      u32 d = (u32)((myk[k] >> sh) & 7);
      vpack |= (u64)d << (3*k);
      u64 inc = 1ull << (16*(d&3));
      c0 += (d & 4) ? 0 : inc;
      c1 += (d & 4) ? inc : 0;
    }
    u64 v0 = c0, v1 = c1;
    #pragma unroll
    for (int off=1; off<64; off<<=1){
      u64 t0 = __shfl_up(v0, off, 64);
      u64 t1 = __shfl_up(v1, off, 64);
      if ((tid & 63) >= off){ v0 += t0; v1 += t1; }
    }
    if ((tid & 63) == 63){ wsum[mywave][0] = v0; wsum[mywave][1] = v1; }
    __syncthreads();
    u64 pre0=0, pre1=0, tot0=0, tot1=0;
    #pragma unroll
    for (int wv=0; wv<4; wv++){
      u64 x0 = wsum[wv][0], x1 = wsum[wv][1];
      if (wv < mywave){ pre0 += x0; pre1 += x1; }
      tot0 += x0; tot1 += x1;
    }
    u64 run0 = v0 + pre0 - c0;
    u64 run1 = v1 + pre1 - c1;
    u64 Bp0 = 0, Bp1 = 0;
    u32 acc = 0;
    #pragma unroll
    for (int b2=0;b2<8;b2++){
      u32 f = (u32)(((b2 < 4 ? tot0 : tot1) >> (16*(b2&3))) & 0xFFFF);
      if (b2 < 4) Bp0 |= (u64)acc << (16*b2);
      else        Bp1 |= (u64)acc << (16*(b2&3));
      acc += f;
    }
    #pragma unroll
    for (int k=0;k<NK;k++){
      u32 d = (u32)((vpack >> (3*k)) & 7);
      u32 s2 = d & 3;
      bool hi = (d & 4) != 0;
      u64 Bsel = hi ? Bp1 : Bp0;
      u64 rsel = hi ? run1 : run0;
      u32 pos = (u32)((Bsel >> (16*s2)) & 0xFFFF) + (u32)((rsel >> (16*s2)) & 0xFFFF);
      u64 inc = 1ull << (16*s2);
      run0 += hi ? 0 : inc;
      run1 += hi ? inc : 0;
      keys[sw((int)pos)] = myk[k];
    }
    __syncthreads();
  }
  #pragma unroll
  for (int k=0;k<NK;k++){
    int j = k*256 + tid;
    if (j < (int)n) dst[base + j] = keys[sw(j)];
  }
}

// streaming per-tile (head, crossHead) counts — vectorized loads, TILE=2048 (8/thread)
__global__ __launch_bounds__(256) void k_tilesum(const u64* __restrict__ A, u64* __restrict__ tileSums){
  __shared__ u64 s[256];
  int tid = threadIdx.x;
  int start = blockIdx.x*TILE + tid*8;
  u64 myk[8];
  if (start + 8 <= NE){
    const ulonglong2* A2 = (const ulonglong2*)(A + start);
    #pragma unroll
    for (int k2=0;k2<4;k2++){ ulonglong2 t = A2[k2]; myk[2*k2]=t.x; myk[2*k2+1]=t.y; }
  } else {
    #pragma unroll
    for (int k=0;k<8;k++) myk[k] = (start+k < NE) ? A[start+k] : 0ull;
  }
  u64 prev = (start > 0 && start <= NE) ? A[start-1] : ~0ull;
  u32 th=0, tc=0;
  #pragma unroll
  for (int k=0;k<8;k++){
    int i = start + k;
    if (i < NE){
      u64 v = myk[k];
      if ((v>>CODESHIFT) != (prev>>CODESHIFT)){
        th++;
        if ((v>>IDXBITS) & 1ull) tc++;
      }
      prev = v;
    }
  }
  s[tid] = ((u64)th<<32) | (u64)tc;
  __syncthreads();
  for (int off=128; off>0; off>>=1){
    if (tid<off) s[tid]+=s[tid+off];
    __syncthreads();
  }
  if (tid==0) tileSums[blockIdx.x] = s[0];
}

// exclusive scan over tiles; tileOff[NTILES] = grand total
__global__ void k_scan_tiles(u64* __restrict__ tileSums, u64* __restrict__ tileOff){
  __shared__ u64 s[256];
  int tid = threadIdx.x;
  u64 carry=0;
  for (int start=0; start<NTILES; start+=256){
    int idx=start+tid;
    u64 x = (idx<NTILES)? tileSums[idx] : 0;
    s[tid]=x; __syncthreads();
    for (int off=1;off<256;off<<=1){
      u64 t=(tid>=off)?s[tid-off]:0;
      __syncthreads();
      s[tid]+=t;
      __syncthreads();
    }
    u64 incl=s[tid], tot=s[255];
    if (idx<NTILES) tileOff[idx] = carry + incl - x;
    carry += tot;
    __syncthreads();
  }
  if (tid==0) tileOff[NTILES] = carry;
}

// streaming pass: crossing flags + staged pairs + dense codes[m].
// TILE=2048 (8/thread); popcount-indexed output positions (no serial chain).
__global__ __launch_bounds__(256) void k_emit_light(const u64* __restrict__ A,
     const u64* __restrict__ tileOff, u64* __restrict__ pairs, u32* __restrict__ cursors,
     u64* __restrict__ codes, float* __restrict__ crossing_out){
  __shared__ u64 wsum[4];
  __shared__ u32 cnt[NBUCK], lcur[NBUCK];
  __shared__ u32 lofs[NBUCK+1];
  __shared__ u32 gbase[NBUCK];
  __shared__ u64 stage[STAGECAP];
  int tid=threadIdx.x, blk=blockIdx.x;
  int lane = tid & 63, wv = tid >> 6;
  int start = blk*TILE + tid*8;
  if (tid < NBUCK){ cnt[tid]=0; lcur[tid]=0; }
  u64 myk[8];
  if (start + 8 <= NE){
    const ulonglong2* A2 = (const ulonglong2*)(A + start);
    #pragma unroll
    for (int k2=0;k2<4;k2++){ ulonglong2 t = A2[k2]; myk[2*k2]=t.x; myk[2*k2+1]=t.y; }
  } else {
    #pragma unroll
    for (int k=0;k<8;k++) myk[k] = (start+k < NE) ? A[start+k] : 0ull;
  }
  u64 prev = (start > 0 && start <= NE) ? A[start-1] : ~0ull;
  u32 headm=0, crossm=0;
  #pragma unroll
  for (int k=0;k<8;k++){
    int i = start + k;
    if (i<NE){
      u64 v = myk[k];
      if ((v>>CODESHIFT) != (prev>>CODESHIFT)) headm |= 1u<<k;
      if ((v>>IDXBITS) & 1ull) crossm |= 1u<<k;
      prev = v;
    }
  }
  __syncthreads();   // cnt/lcur zeroed
  #pragma unroll
  for (int k=0;k<8;k++){
    if ((start+k) < NE && ((crossm>>k)&1u))
      atomicAdd(&cnt[((u32)myk[k] & IDXMASK)>>BSHIFT], 1u);
  }
  u32 th = __popc(headm), tc = __popc(headm & crossm);
  u64 x = ((u64)th<<32)|(u64)tc;
  u64 v = x;
  #pragma unroll
  for (int off=1; off<64; off<<=1){
    u64 t = __shfl_up(v, off, 64);
    if (lane >= off) v += t;
  }
  if (lane == 63) wsum[wv] = v;
  __syncthreads();
  u64 pre = 0;
  #pragma unroll
  for (int w2=0; w2<4; w2++){ u64 s2 = wsum[w2]; if (w2 < wv) pre += s2; }
  u64 excl = v - x + pre;
  if (tid < 64){
    u32 a0 = (2*tid   < NBUCK) ? cnt[2*tid]   : 0;
    u32 a1 = (2*tid+1 < NBUCK) ? cnt[2*tid+1] : 0;
    u32 sp = a0 + a1;
    u32 sv = sp;
    #pragma unroll
    for (int off=1; off<64; off<<=1){
      u32 t = __shfl_up(sv, off, 64);
      if (lane >= off) sv += t;
    }
    u32 basex = sv - sp;
    if (2*tid   < NBUCK) lofs[2*tid]   = basex;
    if (2*tid+1 < NBUCK) lofs[2*tid+1] = basex + a0;
    if (tid == 63) lofs[NBUCK] = sv;
  }
  if (tid < NBUCK) gbase[tid] = atomicAdd(&cursors[tid], cnt[tid]);
  __syncthreads();
  bool use_stage = (lofs[NBUCK] <= STAGECAP);
  u64 baseOff = tileOff[blk] + excl;
  u32 Hbase = (u32)(baseOff>>32);
  u32 Cbase = (u32)(baseOff & 0xFFFFFFFFull);
  u32 hc = headm & crossm;
  #pragma unroll
  for (int k=0;k<8;k++){
    int i = start+k;
    if (i>=NE) break;
    u32 incl = (2u<<k)-1u;
    bool head  = (headm>>k)&1u;
    bool cross = (crossm>>k)&1u;
    u32 Hk = Hbase + __popc(headm & incl);
    u32 Ck = Cbase + __popc(hc & incl);
    if (cross){
      int m = (int)Ck-1;
      u32 orig = (u32)myk[k] & IDXMASK;
      u32 b = orig>>BSHIFT;
      u32 r = atomicAdd(&lcur[b], 1u);
      u64 pr = ((u64)orig<<32) | (u64)(u32)m;
      if (use_stage) stage[lofs[b] + r] = pr;
      else           pairs[(size_t)b*BSZ + gbase[b] + r] = pr;
    }
    if (head){
      crossing_out[Hk-1] = cross ? 1.f : 0.f;
      if (cross) codes[Ck-1] = myk[k]>>CODESHIFT;
    }
  }
  __syncthreads();
  if (use_stage){
    int ncross = (int)lofs[NBUCK];
    for (int j = tid; j < ncross; j += 256){
      u64 pr = stage[j];
      u32 b = (u32)(pr>>32) >> BSHIFT;
      pairs[(size_t)b*BSZ + gbase[b] + (u32)(j - (int)lofs[b])] = pr;
    }
  }
}

// gather-only verts pass; 40KB dummy LDS caps occupancy so psd stays L2-resident
__global__ __launch_bounds__(256) void k_verts(const u64* __restrict__ codes,
     const float4* __restrict__ psd, const u64* __restrict__ totptr, float* __restrict__ verts){
  __shared__ u64 dummy[5120];
  u32 ncross = (u32)(totptr[0] & 0xFFFFFFFFull);
  u32 stride = gridDim.x * blockDim.x;
  for (u32 i = blockIdx.x*blockDim.x + threadIdx.x; i < ncross; i += stride){
    u64 code = codes[i];
    u32 u0 = (u32)(code >> 19), u1 = (u32)(code & 0x7FFFFull);
    float4 a = psd[u0], b = psd[u1];
    float denom = a.w - b.w;
    float w0 = (-b.w)/denom, w1 = a.w/denom;
    verts[3*i+0] = a.x*w0 + b.x*w1;
    verts[3*i+1] = a.y*w0 + b.y*w1;
    verts[3*i+2] = a.z*w0 + b.z*w1;
  }
  if ((int)ncross < -1){ dummy[threadIdx.x] = codes[0]; verts[0] = (float)dummy[255]; }
}

// zero-fill tails: verts[3*ncross .. 21.6M) (incl. dead codes region) and cross[nuniq .. 7.2M)
__global__ void k_tailzero(const u64* __restrict__ totptr,
                           float* __restrict__ verts, float* __restrict__ cross){
  u64 tot = totptr[0];
  u32 nuniq  = (u32)(tot>>32);
  u32 ncross = (u32)(tot & 0xFFFFFFFFull);
  u32 vstart = 3u*ncross;
  u32 vlen = 21600000u - vstart;
  u32 clen = 7200000u - nuniq;
  u32 stride = gridDim.x * blockDim.x;
  for (u32 i = blockIdx.x*blockDim.x + threadIdx.x; i < vlen; i += stride)
    verts[vstart + i] = 0.f;
  for (u32 i = blockIdx.x*blockDim.x + threadIdx.x; i < clen; i += stride)
    cross[nuniq + i] = 0.f;
}

__global__ void k_map_scatter(const u64* __restrict__ pairs, const u32* __restrict__ cursors,
                              float* __restrict__ mapF){
  int b = blockIdx.x / BPB, sub = blockIdx.x % BPB;
  u32 n = cursors[b];
  const u64* p = pairs + (size_t)b*BSZ;
  for (u32 i = (u32)(sub*256 + threadIdx.x); i < n; i += BPB*256){
    u64 v = p[i];
    mapF[(u32)(v>>32)] = (float)(int)(u32)v;
  }
}

// k_faces: triangle-table entries reference only CROSSING edges, always written by map_scatter
__global__ void k_faces(const float* __restrict__ occF, float* faceRegion, float* __restrict__ numt){
  int t = blockIdx.x*blockDim.x + threadIdx.x;
  if (t>=NTET) return;
  int occ = (int)occF[t];
  int ntri = c_numtri[occ];
  float em[6];
  #pragma unroll
  for (int j=0;j<6;j++) em[j] = faceRegion[t*6+j];
  float f[6];
  #pragma unroll
  for (int j=0;j<6;j++){
    int tri = c_tritab[occ][j];
    f[j] = ((j/3) < ntri) ? em[tri] : -1.f;
  }
  #pragma unroll
  for (int j=0;j<6;j++) faceRegion[t*6+j] = f[j];
  numt[t] = (float)ntri;
}

extern "C" void kernel_launch(void* const* d_in, const int* in_sizes, int n_in,
                              void* d_out, int out_size, void* d_ws, size_t ws_size,
                              hipStream_t stream) {
  const float* pos = (const float*)d_in[0];
  const float* sdf = (const float*)d_in[1];
  const int*   tet = (const int*)d_in[2];
  float* out = (float*)d_out;

  // ws layout
  char* w = (char*)d_ws;
  u64* bufA     = (u64*)w;                        // 57,600,000
  u32* hist     = (u32*)(w + 57600000);           // 18,752
  u32* boff     = (u32*)(w + 57618752);           // 18,752
  u32* gcur     = (u32*)(w + 57637504);           // 18,752
  u64* tileSums = (u64*)(w + 57656256);           // 28,128 (3516*8)
  u64* tileOff  = (u64*)(w + 57684384);           // 28,136 (NTILES+1)
  u32* cursors  = (u32*)(w + 57712520);           // 440
  u32* ccur     = (u32*)(w + 57712960);           // 296 -> pad to 57713664
  float4* psd   = (float4*)(w + 57713664);        // 4,800,000
  u64* pairs_ws = (u64*)(w + 62513664);           // 57,600,000 -> ends 120,113,664
  u32* histBlk  = (u32*)pairs_ws;                 // 512*4688*4 (pack-time only)

  u64* bufB  = (u64*)d_out;                       // coarse-partitioned keys (bytes 0..57.6MB)
  u64* codes = (u64*)(out + CODES_ELEM);          // bytes 56MB..86.4MB

  k_pack<<<PK_GRID, 256, 0, stream>>>(tet, sdf, bufA, out + NUMT_OFF, histBlk);
  k_psd<<<(NVERT+255)/256, 256, 0, stream>>>(pos, sdf, psd);

  k_reduce_hist<<<(NBUCKS+255)/256, 256, 0, stream>>>(histBlk, hist);
  k_scan_buckets<<<1, 1024, 0, stream>>>(hist, boff, gcur, ccur);

  // pass 1a: coarse partition bufA -> bufB ; pass 1b: fine partition bufB -> bufA
  k_coarse_scatter<<<P1_GRID, P1_TPB, 0, stream>>>(bufA, bufB, ccur);
  k_fine_scatter<<<NCOARSE*FS_SUB, P1_TPB, 0, stream>>>(bufB, bufA, boff, gcur);

  // pass 2: in-place in-LDS sort of each fine bucket (size-classed)
  k_sort_bucket<4><<<NBUCKS, 256, 0, stream>>>(bufA, bufA, hist, boff);
  k_sort_bucket<8><<<NBUCKS, 256, 0, stream>>>(bufA, bufA, hist, boff);
  k_sort_bucket<12><<<NBUCKS, 256, 0, stream>>>(bufA, bufA, hist, boff);
  k_sort_bucket<16><<<NBUCKS, 256, 0, stream>>>(bufA, bufA, hist, boff);

  k_tilesum<<<NTILES, 256, 0, stream>>>(bufA, tileSums);
  k_scan_tiles<<<1, 256, 0, stream>>>(tileSums, tileOff);

  hipMemsetAsync(cursors, 0, NBUCK*sizeof(u32), stream);

  k_emit_light<<<NTILES, 256, 0, stream>>>(bufA, tileOff, pairs_ws, cursors,
                                           codes, out + CROSS_OFF);

  k_verts<<<1024, 256, 0, stream>>>(codes, psd, tileOff + NTILES, out + VERTS_OFF);
  k_tailzero<<<2048, 256, 0, stream>>>(tileOff + NTILES, out + VERTS_OFF, out + CROSS_OFF);

  k_map_scatter<<<NBUCK*BPB, 256, 0, stream>>>(pairs_ws, cursors, out + FACES_OFF);
  k_faces<<<(NTET+255)/256, 256, 0, stream>>>(out + NUMT_OFF, out + FACES_OFF, out + NUMT_OFF);
}

// Round 22
// 524.403 us; speedup vs baseline: 1.0447x; 1.0447x over previous
//
#include <hip/hip_runtime.h>
#include <stdint.h>

typedef unsigned long long u64;
typedef unsigned int u32;

#define NVERT 300000
#define NTET  1200000
#define NE    (NTET*6)              // 7,200,000 edges
#define TILE  4096
#define NTILES ((NE + TILE - 1)/TILE)   // 1758
#define IDXBITS 23
#define IDXMASK ((1u<<IDXBITS)-1)
#define CODESHIFT 24                // key = code<<24 | cross<<23 | idx ; code = e0<<19 | e1
#define NBUCKS 4688                 // fine bucket = key>>49 = e0>>6
#define BUCKSHIFT 49
#define NCOARSE 74                  // coarse bucket = key>>55 = e0>>12 (64 fine per coarse)
#define COARSESHIFT 55

// pack geometry
#define PK_GRID 512

// pass-1a geometry (register-held keys, 220 blocks)
#define P1_TPB  1024
#define P1_KPT  32
#define P1_KEYS (P1_TPB*P1_KPT)     // 32768
#define P1_GRID ((NE + P1_KEYS - 1)/P1_KEYS)   // 220

// pass-1b geometry
#define FS_SUB 8
#define FS_CH  32768

// mapping-scatter buckets (faces mapping)
#define BSHIFT 16
#define BSZ    65536
#define NBUCK  110
#define BPB    8
#define STAGECAP 2240               // TILE/2 mean + 6 sigma

// output layout (float32 elements)
#define VERTS_OFF 0
#define FACES_OFF 21600000
#define NUMT_OFF  28800000
#define CROSS_OFF 30000000
#define CODES_ELEM 14000000         // codes at bytes 56MB..86.4MB of d_out

__constant__ int c_ea[6] = {0,0,0,1,1,2};
__constant__ int c_eb[6] = {1,2,3,2,3,3};
__constant__ int c_numtri[16] = {0,1,1,2,1,2,2,1,1,2,2,1,2,1,1,0};
__constant__ int c_tritab[16][6] = {
 {-1,-1,-1,-1,-1,-1},{1,0,2,-1,-1,-1},{4,0,3,-1,-1,-1},{1,4,2,1,3,4},
 {3,1,5,-1,-1,-1},{2,3,0,2,5,3},{1,4,0,1,5,4},{4,2,5,-1,-1,-1},
 {4,5,2,-1,-1,-1},{4,1,0,4,5,1},{3,2,0,3,5,2},{1,3,5,-1,-1,-1},
 {4,1,2,4,3,1},{3,0,4,-1,-1,-1},{2,0,1,-1,-1,-1},{-1,-1,-1,-1,-1,-1}};

__device__ __forceinline__ int sw(int j){ return j ^ ((j >> 4) & 15); }

// grid-stride pack: 6 keys (LDS-staged coalesced) + occ nibble + per-block NON-ATOMIC hist row
__global__ __launch_bounds__(256) void k_pack(const int* __restrict__ tet, const float* __restrict__ sdf,
                       u64* __restrict__ dst, float* __restrict__ occF, u32* __restrict__ histBlk){
  __shared__ u32 h[NBUCKS];   // 18.75KB
  __shared__ u64 lk[256*6];   // 12KB key staging
  int tid = threadIdx.x;
  for (int r=tid; r<NBUCKS; r+=256) h[r]=0;
  __syncthreads();
  for (int t0 = blockIdx.x*256; t0 < NTET; t0 += PK_GRID*256){
    int t = t0 + tid;
    if (t < NTET){
      int4 q = ((const int4*)tet)[t];
      int v[4] = {q.x, q.y, q.z, q.w};
      u32 o[4];
      int occ = 0;
      #pragma unroll
      for (int j=0;j<4;j++){ o[j] = sdf[v[j]] > 0.f ? 1u : 0u; occ |= (int)o[j] << j; }
      occF[t] = (float)occ;
      u64 base = (u64)t*6;
      #pragma unroll
      for (int k=0;k<6;k++){
        int a = v[c_ea[k]], b = v[c_eb[k]];
        u64 cross = (o[c_ea[k]] != o[c_eb[k]]) ? 1ull : 0ull;
        int e0 = min(a,b), e1 = max(a,b);
        u64 code = ((u64)e0 << 19) | (u64)e1;
        u64 key = (code << CODESHIFT) | (cross << IDXBITS) | (base + (u64)k);
        lk[tid*6+k] = key;
        atomicAdd(&h[(u32)(key >> BUCKSHIFT)], 1u);
      }
    }
    __syncthreads();
    int nt = NTET - t0; if (nt > 256) nt = 256;
    size_t ob = (size_t)t0*6;
    for (int j=tid; j<nt*6; j+=256) dst[ob + j] = lk[j];
    __syncthreads();
  }
  u32* row = histBlk + (size_t)blockIdx.x * NBUCKS;
  for (int r=tid; r<NBUCKS; r+=256) row[r] = h[r];
}

// sum the 512 per-block hist rows (coalesced)
__global__ void k_reduce_hist(const u32* __restrict__ histBlk, u32* __restrict__ hist){
  int b = blockIdx.x*256 + threadIdx.x;
  if (b >= NBUCKS) return;
  u32 s = 0;
  for (int r=0;r<PK_GRID;r++) s += histBlk[(size_t)r*NBUCKS + b];
  hist[b] = s;
}

__global__ void k_psd(const float* __restrict__ pos, const float* __restrict__ sdf,
                      float4* __restrict__ psd){
  int v = blockIdx.x*blockDim.x + threadIdx.x;
  if (v < NVERT) psd[v] = make_float4(pos[3*v], pos[3*v+1], pos[3*v+2], sdf[v]);
}

// exclusive scan over fine buckets; writes boff, fine cursors AND coarse cursors
__global__ __launch_bounds__(1024) void k_scan_buckets(const u32* __restrict__ hist,
     u32* __restrict__ boff, u32* __restrict__ gcur, u32* __restrict__ ccur){
  __shared__ u32 s[1024];
  int tid = threadIdx.x;
  u32 carry = 0;
  for (int start=0; start<NBUCKS; start+=1024){
    int idx = start + tid;
    u32 x = (idx < NBUCKS) ? hist[idx] : 0;
    s[tid] = x; __syncthreads();
    for (int off=1; off<1024; off<<=1){
      u32 t = (tid >= off) ? s[tid-off] : 0;
      __syncthreads();
      s[tid] += t;
      __syncthreads();
    }
    u32 excl = carry + s[tid] - x;
    if (idx < NBUCKS){
      boff[idx] = excl; gcur[idx] = excl;
      if ((idx & 63) == 0) ccur[idx >> 6] = excl;
    }
    carry += s[1023];
    __syncthreads();
  }
}

// pass 1a: coarse partition (74 buckets). 32768 keys/block; runs ~443 keys -> coalesced
__global__ __launch_bounds__(P1_TPB) void k_coarse_scatter(const u64* __restrict__ src,
     u64* __restrict__ dst, u32* __restrict__ ccur){
  __shared__ u32 h[NCOARSE];
  int tid = threadIdx.x;
  if (tid < NCOARSE) h[tid]=0;
  __syncthreads();
  size_t gi = (size_t)blockIdx.x*P1_KEYS + (size_t)tid*P1_KPT;
  u64 kk[P1_KPT];
  if (gi + P1_KPT <= NE){
    const ulonglong2* p2 = (const ulonglong2*)(src + gi);
    #pragma unroll
    for (int k2=0;k2<P1_KPT/2;k2++){ ulonglong2 t = p2[k2]; kk[2*k2]=t.x; kk[2*k2+1]=t.y; }
  } else {
    #pragma unroll
    for (int k=0;k<P1_KPT;k++) kk[k] = (gi+k < NE) ? src[gi+k] : ~0ull;
  }
  #pragma unroll
  for (int k=0;k<P1_KPT;k++){
    if (gi+k < NE) atomicAdd(&h[(u32)(kk[k] >> COARSESHIFT)], 1u);
  }
  __syncthreads();
  if (tid < NCOARSE){
    u32 c = h[tid];
    h[tid] = c ? atomicAdd(&ccur[tid], c) : 0u;
  }
  __syncthreads();
  #pragma unroll
  for (int k=0;k<P1_KPT;k++){
    if (gi+k < NE){
      u32 b = (u32)(kk[k] >> COARSESHIFT);
      u32 p = atomicAdd(&h[b], 1u);
      dst[p] = kk[k];
    }
  }
}

// pass 1b: fine partition within each coarse region. grid = NCOARSE*FS_SUB.
__global__ __launch_bounds__(P1_TPB) void k_fine_scatter(const u64* __restrict__ src,
     u64* __restrict__ dst, const u32* __restrict__ boff, u32* __restrict__ gcur){
  __shared__ u32 h[64];
  __shared__ u32 rb[64];
  int c = blockIdx.x >> 3, sub = blockIdx.x & (FS_SUB-1);
  int tid = threadIdx.x;
  u32 startc = boff[c*64];
  u32 endc = (c == NCOARSE-1) ? (u32)NE : boff[(c+1)*64];
  u32 size = endc - startc;
  u32 shareLen = (size + FS_SUB - 1) / FS_SUB;
  u32 s0 = startc + sub*shareLen;
  u32 s1 = s0 + shareLen; if (s1 > endc) s1 = endc;
  if (s0 >= s1) return;
  for (u32 base = s0; base < s1; base += FS_CH){
    u32 lim = base + FS_CH; if (lim > s1) lim = s1;
    if (tid < 64) h[tid] = 0;
    __syncthreads();
    for (u32 i = base + tid; i < lim; i += P1_TPB)
      atomicAdd(&h[(u32)(src[i] >> BUCKSHIFT) & 63u], 1u);
    __syncthreads();
    if (tid < 64){
      u32 cc = h[tid];
      rb[tid] = cc ? atomicAdd(&gcur[c*64 + tid], cc) : 0u;
      h[tid] = 0;
    }
    __syncthreads();
    for (u32 i = base + tid; i < lim; i += P1_TPB){
      u64 v = src[i];
      u32 f = (u32)(v >> BUCKSHIFT) & 63u;
      u32 p = rb[f] + atomicAdd(&h[f], 1u);
      dst[p] = v;
    }
    __syncthreads();
  }
}

// pass 2: full in-LDS sort of one bucket (IN-PLACE). Size-classed NK in {4,8,12,16}.
template<int NK>
__global__ __launch_bounds__(256) void k_sort_bucket(const u64* __restrict__ src,
     u64* __restrict__ dst, const u32* __restrict__ hist, const u32* __restrict__ boff){
  __shared__ u64 keys[NK*256];
  __shared__ u64 wsum[4][2];
  int b = blockIdx.x, tid = threadIdx.x;
  u32 n = hist[b];
  if (n == 0) return;
  if (NK == 4  && n > 1024) return;
  if (NK == 8  && (n <= 1024 || n > 2048)) return;
  if (NK == 12 && (n <= 2048 || n > 3072)) return;
  if (NK == 16 && n <= 3072) return;
  u32 base = boff[b];
  #pragma unroll
  for (int k=0;k<NK;k++){
    int j = k*256 + tid;
    keys[sw(j)] = (j < (int)n) ? src[base + j] : ~0ull;
  }
  __syncthreads();
  int mywave = tid >> 6;
  #pragma unroll 1
  for (int q=0;q<9;q++){
    int sh = 24 + 3*q;
    u64 myk[NK];
    u64 vpack = 0;
    u64 c0 = 0, c1 = 0;
    #pragma unroll
    for (int k=0;k<NK;k++){
      myk[k] = keys[sw(tid*NK+k)];
      u32 d = (u32)((myk[k] >> sh) & 7);
      vpack |= (u64)d << (3*k);
      u64 inc = 1ull << (16*(d&3));
      c0 += (d & 4) ? 0 : inc;
      c1 += (d & 4) ? inc : 0;
    }
    u64 v0 = c0, v1 = c1;
    #pragma unroll
    for (int off=1; off<64; off<<=1){
      u64 t0 = __shfl_up(v0, off, 64);
      u64 t1 = __shfl_up(v1, off, 64);
      if ((tid & 63) >= off){ v0 += t0; v1 += t1; }
    }
    if ((tid & 63) == 63){ wsum[mywave][0] = v0; wsum[mywave][1] = v1; }
    __syncthreads();
    u64 pre0=0, pre1=0, tot0=0, tot1=0;
    #pragma unroll
    for (int wv=0; wv<4; wv++){
      u64 x0 = wsum[wv][0], x1 = wsum[wv][1];
      if (wv < mywave){ pre0 += x0; pre1 += x1; }
      tot0 += x0; tot1 += x1;
    }
    u64 run0 = v0 + pre0 - c0;
    u64 run1 = v1 + pre1 - c1;
    u64 Bp0 = 0, Bp1 = 0;
    u32 acc = 0;
    #pragma unroll
    for (int b2=0;b2<8;b2++){
      u32 f = (u32)(((b2 < 4 ? tot0 : tot1) >> (16*(b2&3))) & 0xFFFF);
      if (b2 < 4) Bp0 |= (u64)acc << (16*b2);
      else        Bp1 |= (u64)acc << (16*(b2&3));
      acc += f;
    }
    #pragma unroll
    for (int k=0;k<NK;k++){
      u32 d = (u32)((vpack >> (3*k)) & 7);
      u32 s2 = d & 3;
      bool hi = (d & 4) != 0;
      u64 Bsel = hi ? Bp1 : Bp0;
      u64 rsel = hi ? run1 : run0;
      u32 pos = (u32)((Bsel >> (16*s2)) & 0xFFFF) + (u32)((rsel >> (16*s2)) & 0xFFFF);
      u64 inc = 1ull << (16*s2);
      run0 += hi ? 0 : inc;
      run1 += hi ? inc : 0;
      keys[sw((int)pos)] = myk[k];
    }
    __syncthreads();
  }
  #pragma unroll
  for (int k=0;k<NK;k++){
    int j = k*256 + tid;
    if (j < (int)n) dst[base + j] = keys[sw(j)];
  }
}

// streaming per-tile (head, crossHead) counts — vectorized loads
__global__ __launch_bounds__(256) void k_tilesum(const u64* __restrict__ A, u64* __restrict__ tileSums){
  __shared__ u64 s[256];
  int tid = threadIdx.x;
  int start = blockIdx.x*TILE + tid*16;
  u64 myk[16];
  if (start < NE){
    const ulonglong2* A2 = (const ulonglong2*)(A + start);
    #pragma unroll
    for (int k2=0;k2<8;k2++){ ulonglong2 t = A2[k2]; myk[2*k2]=t.x; myk[2*k2+1]=t.y; }
  } else {
    #pragma unroll
    for (int k=0;k<16;k++) myk[k]=0;
  }
  u64 prev = (start > 0 && start <= NE) ? A[start-1] : ~0ull;
  u32 th=0, tc=0;
  #pragma unroll
  for (int k=0;k<16;k++){
    int i = start + k;
    if (i < NE){
      u64 v = myk[k];
      if ((v>>CODESHIFT) != (prev>>CODESHIFT)){
        th++;
        if ((v>>IDXBITS) & 1ull) tc++;
      }
      prev = v;
    }
  }
  s[tid] = ((u64)th<<32) | (u64)tc;
  __syncthreads();
  for (int off=128; off>0; off>>=1){
    if (tid<off) s[tid]+=s[tid+off];
    __syncthreads();
  }
  if (tid==0) tileSums[blockIdx.x] = s[0];
}

// exclusive scan over tiles; tileOff[NTILES] = grand total
__global__ void k_scan_tiles(u64* __restrict__ tileSums, u64* __restrict__ tileOff){
  __shared__ u64 s[256];
  int tid = threadIdx.x;
  u64 carry=0;
  for (int start=0; start<NTILES; start+=256){
    int idx=start+tid;
    u64 x = (idx<NTILES)? tileSums[idx] : 0;
    s[tid]=x; __syncthreads();
    for (int off=1;off<256;off<<=1){
      u64 t=(tid>=off)?s[tid-off]:0;
      __syncthreads();
      s[tid]+=t;
      __syncthreads();
    }
    u64 incl=s[tid], tot=s[255];
    if (idx<NTILES) tileOff[idx] = carry + incl - x;
    carry += tot;
    __syncthreads();
  }
  if (tid==0) tileOff[NTILES] = carry;
}

// streaming pass: crossing flags + staged pairs + dense codes[m].
// TILE=4096 (16/thread); popcount-indexed output positions (no serial chain).
__global__ __launch_bounds__(256) void k_emit_light(const u64* __restrict__ A,
     const u64* __restrict__ tileOff, u64* __restrict__ pairs, u32* __restrict__ cursors,
     u64* __restrict__ codes, float* __restrict__ crossing_out){
  __shared__ u64 wsum[4];
  __shared__ u32 cnt[NBUCK], lcur[NBUCK];
  __shared__ u32 lofs[NBUCK+1];
  __shared__ u32 gbase[NBUCK];
  __shared__ u64 stage[STAGECAP];
  int tid=threadIdx.x, blk=blockIdx.x;
  int lane = tid & 63, wv = tid >> 6;
  int start = blk*TILE + tid*16;
  if (tid < NBUCK){ cnt[tid]=0; lcur[tid]=0; }
  u64 myk[16];
  if (start < NE){
    const ulonglong2* A2 = (const ulonglong2*)(A + start);
    #pragma unroll
    for (int k2=0;k2<8;k2++){ ulonglong2 t = A2[k2]; myk[2*k2]=t.x; myk[2*k2+1]=t.y; }
  } else {
    #pragma unroll
    for (int k=0;k<16;k++) myk[k]=0;
  }
  u64 prev = (start > 0 && start <= NE) ? A[start-1] : ~0ull;
  u32 headm=0, crossm=0;
  #pragma unroll
  for (int k=0;k<16;k++){
    int i = start + k;
    if (i<NE){
      u64 v = myk[k];
      if ((v>>CODESHIFT) != (prev>>CODESHIFT)) headm |= 1u<<k;
      if ((v>>IDXBITS) & 1ull) crossm |= 1u<<k;
      prev = v;
    }
  }
  __syncthreads();   // cnt/lcur zeroed
  #pragma unroll
  for (int k=0;k<16;k++){
    if ((start+k) < NE && ((crossm>>k)&1u))
      atomicAdd(&cnt[((u32)myk[k] & IDXMASK)>>BSHIFT], 1u);
  }
  u32 th = __popc(headm), tc = __popc(headm & crossm);
  u64 x = ((u64)th<<32)|(u64)tc;
  u64 v = x;
  #pragma unroll
  for (int off=1; off<64; off<<=1){
    u64 t = __shfl_up(v, off, 64);
    if (lane >= off) v += t;
  }
  if (lane == 63) wsum[wv] = v;
  __syncthreads();
  u64 pre = 0;
  #pragma unroll
  for (int w2=0; w2<4; w2++){ u64 s2 = wsum[w2]; if (w2 < wv) pre += s2; }
  u64 excl = v - x + pre;
  if (tid < 64){
    u32 a0 = (2*tid   < NBUCK) ? cnt[2*tid]   : 0;
    u32 a1 = (2*tid+1 < NBUCK) ? cnt[2*tid+1] : 0;
    u32 sp = a0 + a1;
    u32 sv = sp;
    #pragma unroll
    for (int off=1; off<64; off<<=1){
      u32 t = __shfl_up(sv, off, 64);
      if (lane >= off) sv += t;
    }
    u32 basex = sv - sp;
    if (2*tid   < NBUCK) lofs[2*tid]   = basex;
    if (2*tid+1 < NBUCK) lofs[2*tid+1] = basex + a0;
    if (tid == 63) lofs[NBUCK] = sv;
  }
  if (tid < NBUCK) gbase[tid] = atomicAdd(&cursors[tid], cnt[tid]);
  __syncthreads();
  bool use_stage = (lofs[NBUCK] <= STAGECAP);
  u64 baseOff = tileOff[blk] + excl;
  u32 Hbase = (u32)(baseOff>>32);
  u32 Cbase = (u32)(baseOff & 0xFFFFFFFFull);
  u32 hc = headm & crossm;
  #pragma unroll
  for (int k=0;k<16;k++){
    int i = start+k;
    if (i>=NE) break;
    u32 incl = (2u<<k)-1u;
    bool head  = (headm>>k)&1u;
    bool cross = (crossm>>k)&1u;
    u32 Hk = Hbase + __popc(headm & incl);
    u32 Ck = Cbase + __popc(hc & incl);
    if (cross){
      int m = (int)Ck-1;
      u32 orig = (u32)myk[k] & IDXMASK;
      u32 b = orig>>BSHIFT;
      u32 r = atomicAdd(&lcur[b], 1u);
      u64 pr = ((u64)orig<<32) | (u64)(u32)m;
      if (use_stage) stage[lofs[b] + r] = pr;
      else           pairs[(size_t)b*BSZ + gbase[b] + r] = pr;
    }
    if (head){
      crossing_out[Hk-1] = cross ? 1.f : 0.f;
      if (cross) codes[Ck-1] = myk[k]>>CODESHIFT;
    }
  }
  __syncthreads();
  if (use_stage){
    int ncross = (int)lofs[NBUCK];
    for (int j = tid; j < ncross; j += 256){
      u64 pr = stage[j];
      u32 b = (u32)(pr>>32) >> BSHIFT;
      pairs[(size_t)b*BSZ + gbase[b] + (u32)(j - (int)lofs[b])] = pr;
    }
  }
}

// gather-only verts pass; 40KB dummy LDS caps occupancy so psd stays L2-resident
__global__ __launch_bounds__(256) void k_verts(const u64* __restrict__ codes,
     const float4* __restrict__ psd, const u64* __restrict__ totptr, float* __restrict__ verts){
  __shared__ u64 dummy[5120];
  u32 ncross = (u32)(totptr[0] & 0xFFFFFFFFull);
  u32 stride = gridDim.x * blockDim.x;
  for (u32 i = blockIdx.x*blockDim.x + threadIdx.x; i < ncross; i += stride){
    u64 code = codes[i];
    u32 u0 = (u32)(code >> 19), u1 = (u32)(code & 0x7FFFFull);
    float4 a = psd[u0], b = psd[u1];
    float denom = a.w - b.w;
    float w0 = (-b.w)/denom, w1 = a.w/denom;
    verts[3*i+0] = a.x*w0 + b.x*w1;
    verts[3*i+1] = a.y*w0 + b.y*w1;
    verts[3*i+2] = a.z*w0 + b.z*w1;
  }
  if ((int)ncross < -1){ dummy[threadIdx.x] = codes[0]; verts[0] = (float)dummy[255]; }
}

// zero-fill tails: verts[3*ncross .. 21.6M) (incl. dead codes region) and cross[nuniq .. 7.2M)
__global__ void k_tailzero(const u64* __restrict__ totptr,
                           float* __restrict__ verts, float* __restrict__ cross){
  u64 tot = totptr[0];
  u32 nuniq  = (u32)(tot>>32);
  u32 ncross = (u32)(tot & 0xFFFFFFFFull);
  u32 vstart = 3u*ncross;
  u32 vlen = 21600000u - vstart;
  u32 clen = 7200000u - nuniq;
  u32 stride = gridDim.x * blockDim.x;
  for (u32 i = blockIdx.x*blockDim.x + threadIdx.x; i < vlen; i += stride)
    verts[vstart + i] = 0.f;
  for (u32 i = blockIdx.x*blockDim.x + threadIdx.x; i < clen; i += stride)
    cross[nuniq + i] = 0.f;
}

__global__ void k_map_scatter(const u64* __restrict__ pairs, const u32* __restrict__ cursors,
                              float* __restrict__ mapF){
  int b = blockIdx.x / BPB, sub = blockIdx.x % BPB;
  u32 n = cursors[b];
  const u64* p = pairs + (size_t)b*BSZ;
  for (u32 i = (u32)(sub*256 + threadIdx.x); i < n; i += BPB*256){
    u64 v = p[i];
    mapF[(u32)(v>>32)] = (float)(int)(u32)v;
  }
}

// k_faces: triangle-table entries reference only CROSSING edges, always written by map_scatter
__global__ void k_faces(const float* __restrict__ occF, float* faceRegion, float* __restrict__ numt){
  int t = blockIdx.x*blockDim.x + threadIdx.x;
  if (t>=NTET) return;
  int occ = (int)occF[t];
  int ntri = c_numtri[occ];
  float em[6];
  #pragma unroll
  for (int j=0;j<6;j++) em[j] = faceRegion[t*6+j];
  float f[6];
  #pragma unroll
  for (int j=0;j<6;j++){
    int tri = c_tritab[occ][j];
    f[j] = ((j/3) < ntri) ? em[tri] : -1.f;
  }
  #pragma unroll
  for (int j=0;j<6;j++) faceRegion[t*6+j] = f[j];
  numt[t] = (float)ntri;
}

extern "C" void kernel_launch(void* const* d_in, const int* in_sizes, int n_in,
                              void* d_out, int out_size, void* d_ws, size_t ws_size,
                              hipStream_t stream) {
  const float* pos = (const float*)d_in[0];
  const float* sdf = (const float*)d_in[1];
  const int*   tet = (const int*)d_in[2];
  float* out = (float*)d_out;

  // ws layout
  char* w = (char*)d_ws;
  u64* bufA     = (u64*)w;                        // 57,600,000
  u32* hist     = (u32*)(w + 57600000);           // 18,752
  u32* boff     = (u32*)(w + 57618752);           // 18,752
  u32* gcur     = (u32*)(w + 57637504);           // 18,752
  u64* tileSums = (u64*)(w + 57656256);           // 14,064
  u64* tileOff  = (u64*)(w + 57670320);           // 14,072 (NTILES+1)
  u32* cursors  = (u32*)(w + 57684392);           // 440
  u32* ccur     = (u32*)(w + 57684832);           // 296 -> pad to 57685504
  float4* psd   = (float4*)(w + 57685504);        // 4,800,000
  u64* pairs_ws = (u64*)(w + 62485504);           // 57,600,000 -> ends 120,085,504
  u32* histBlk  = (u32*)pairs_ws;                 // 512*4688*4 (pack-time only)

  u64* bufB  = (u64*)d_out;                       // coarse-partitioned keys (bytes 0..57.6MB)
  u64* codes = (u64*)(out + CODES_ELEM);          // bytes 56MB..86.4MB

  k_pack<<<PK_GRID, 256, 0, stream>>>(tet, sdf, bufA, out + NUMT_OFF, histBlk);
  k_psd<<<(NVERT+255)/256, 256, 0, stream>>>(pos, sdf, psd);

  k_reduce_hist<<<(NBUCKS+255)/256, 256, 0, stream>>>(histBlk, hist);
  k_scan_buckets<<<1, 1024, 0, stream>>>(hist, boff, gcur, ccur);

  // pass 1a: coarse partition bufA -> bufB ; pass 1b: fine partition bufB -> bufA
  k_coarse_scatter<<<P1_GRID, P1_TPB, 0, stream>>>(bufA, bufB, ccur);
  k_fine_scatter<<<NCOARSE*FS_SUB, P1_TPB, 0, stream>>>(bufB, bufA, boff, gcur);

  // pass 2: in-place in-LDS sort of each fine bucket (size-classed)
  k_sort_bucket<4><<<NBUCKS, 256, 0, stream>>>(bufA, bufA, hist, boff);
  k_sort_bucket<8><<<NBUCKS, 256, 0, stream>>>(bufA, bufA, hist, boff);
  k_sort_bucket<12><<<NBUCKS, 256, 0, stream>>>(bufA, bufA, hist, boff);
  k_sort_bucket<16><<<NBUCKS, 256, 0, stream>>>(bufA, bufA, hist, boff);

  k_tilesum<<<NTILES, 256, 0, stream>>>(bufA, tileSums);
  k_scan_tiles<<<1, 256, 0, stream>>>(tileSums, tileOff);

  hipMemsetAsync(cursors, 0, NBUCK*sizeof(u32), stream);

  k_emit_light<<<NTILES, 256, 0, stream>>>(bufA, tileOff, pairs_ws, cursors,
                                           codes, out + CROSS_OFF);

  k_verts<<<1024, 256, 0, stream>>>(codes, psd, tileOff + NTILES, out + VERTS_OFF);
  k_tailzero<<<2048, 256, 0, stream>>>(tileOff + NTILES, out + VERTS_OFF, out + CROSS_OFF);

  k_map_scatter<<<NBUCK*BPB, 256, 0, stream>>>(pairs_ws, cursors, out + FACES_OFF);
  k_faces<<<(NTET+255)/256, 256, 0, stream>>>(out + NUMT_OFF, out + FACES_OFF, out + NUMT_OFF);
}

// Round 23
// 516.945 us; speedup vs baseline: 1.0598x; 1.0144x over previous
//
#include <hip/hip_runtime.h>
#include <stdint.h>

typedef unsigned long long u64;
typedef unsigned int u32;

#define NVERT 300000
#define NTET  1200000
#define NE    (NTET*6)              // 7,200,000 edges
#define TILE  4096
#define NTILES ((NE + TILE - 1)/TILE)   // 1758
#define IDXBITS 23
#define IDXMASK ((1u<<IDXBITS)-1)
#define CODESHIFT 24                // key = code<<24 | cross<<23 | idx ; code = e0<<19 | e1
#define NBUCKS 4688                 // fine bucket = key>>49 = e0>>6
#define BUCKSHIFT 49
#define NCOARSE 74                  // coarse bucket = key>>55 = e0>>12 (64 fine per coarse)
#define COARSESHIFT 55

// pack geometry
#define PK_GRID 512

// pass-1a geometry (register-held keys, 220 blocks)
#define P1_TPB  1024
#define P1_KPT  32
#define P1_KEYS (P1_TPB*P1_KPT)     // 32768
#define P1_GRID ((NE + P1_KEYS - 1)/P1_KEYS)   // 220

// pass-1b geometry
#define FS_SUB 8
#define FS_CH  32768

// mapping-scatter buckets (faces mapping); PADDED cursors: one per 64B line
#define BSHIFT 16
#define BSZ    65536
#define NBUCK  110
#define BPB    8
#define STAGECAP 2240
#define CPAD 16                     // u32 stride between cursors (64B)

// output layout (float32 elements)
#define VERTS_OFF 0
#define FACES_OFF 21600000
#define NUMT_OFF  28800000
#define CROSS_OFF 30000000
#define CODES_ELEM 14000000         // codes at bytes 56MB..86.4MB of d_out

__constant__ int c_ea[6] = {0,0,0,1,1,2};
__constant__ int c_eb[6] = {1,2,3,2,3,3};
__constant__ int c_numtri[16] = {0,1,1,2,1,2,2,1,1,2,2,1,2,1,1,0};
__constant__ int c_tritab[16][6] = {
 {-1,-1,-1,-1,-1,-1},{1,0,2,-1,-1,-1},{4,0,3,-1,-1,-1},{1,4,2,1,3,4},
 {3,1,5,-1,-1,-1},{2,3,0,2,5,3},{1,4,0,1,5,4},{4,2,5,-1,-1,-1},
 {4,5,2,-1,-1,-1},{4,1,0,4,5,1},{3,2,0,3,5,2},{1,3,5,-1,-1,-1},
 {4,1,2,4,3,1},{3,0,4,-1,-1,-1},{2,0,1,-1,-1,-1},{-1,-1,-1,-1,-1,-1}};

__device__ __forceinline__ int sw(int j){ return j ^ ((j >> 4) & 15); }

// grid-stride pack: 6 keys (LDS-staged coalesced) + occ nibble + per-block NON-ATOMIC hist row
__global__ __launch_bounds__(256) void k_pack(const int* __restrict__ tet, const float* __restrict__ sdf,
                       u64* __restrict__ dst, float* __restrict__ occF, u32* __restrict__ histBlk){
  __shared__ u32 h[NBUCKS];   // 18.75KB
  __shared__ u64 lk[256*6];   // 12KB key staging
  int tid = threadIdx.x;
  for (int r=tid; r<NBUCKS; r+=256) h[r]=0;
  __syncthreads();
  for (int t0 = blockIdx.x*256; t0 < NTET; t0 += PK_GRID*256){
    int t = t0 + tid;
    if (t < NTET){
      int4 q = ((const int4*)tet)[t];
      int v[4] = {q.x, q.y, q.z, q.w};
      u32 o[4];
      int occ = 0;
      #pragma unroll
      for (int j=0;j<4;j++){ o[j] = sdf[v[j]] > 0.f ? 1u : 0u; occ |= (int)o[j] << j; }
      occF[t] = (float)occ;
      u64 base = (u64)t*6;
      #pragma unroll
      for (int k=0;k<6;k++){
        int a = v[c_ea[k]], b = v[c_eb[k]];
        u64 cross = (o[c_ea[k]] != o[c_eb[k]]) ? 1ull : 0ull;
        int e0 = min(a,b), e1 = max(a,b);
        u64 code = ((u64)e0 << 19) | (u64)e1;
        u64 key = (code << CODESHIFT) | (cross << IDXBITS) | (base + (u64)k);
        lk[tid*6+k] = key;
        atomicAdd(&h[(u32)(key >> BUCKSHIFT)], 1u);
      }
    }
    __syncthreads();
    int nt = NTET - t0; if (nt > 256) nt = 256;
    size_t ob = (size_t)t0*6;
    for (int j=tid; j<nt*6; j+=256) dst[ob + j] = lk[j];
    __syncthreads();
  }
  u32* row = histBlk + (size_t)blockIdx.x * NBUCKS;
  for (int r=tid; r<NBUCKS; r+=256) row[r] = h[r];
}

// sum the 512 per-block hist rows (coalesced)
__global__ void k_reduce_hist(const u32* __restrict__ histBlk, u32* __restrict__ hist){
  int b = blockIdx.x*256 + threadIdx.x;
  if (b >= NBUCKS) return;
  u32 s = 0;
  for (int r=0;r<PK_GRID;r++) s += histBlk[(size_t)r*NBUCKS + b];
  hist[b] = s;
}

__global__ void k_psd(const float* __restrict__ pos, const float* __restrict__ sdf,
                      float4* __restrict__ psd){
  int v = blockIdx.x*blockDim.x + threadIdx.x;
  if (v < NVERT) psd[v] = make_float4(pos[3*v], pos[3*v+1], pos[3*v+2], sdf[v]);
}

// exclusive scan over fine buckets; writes boff, fine cursors AND padded coarse cursors
__global__ __launch_bounds__(1024) void k_scan_buckets(const u32* __restrict__ hist,
     u32* __restrict__ boff, u32* __restrict__ gcur, u32* __restrict__ ccur){
  __shared__ u32 s[1024];
  int tid = threadIdx.x;
  u32 carry = 0;
  for (int start=0; start<NBUCKS; start+=1024){
    int idx = start + tid;
    u32 x = (idx < NBUCKS) ? hist[idx] : 0;
    s[tid] = x; __syncthreads();
    for (int off=1; off<1024; off<<=1){
      u32 t = (tid >= off) ? s[tid-off] : 0;
      __syncthreads();
      s[tid] += t;
      __syncthreads();
    }
    u32 excl = carry + s[tid] - x;
    if (idx < NBUCKS){
      boff[idx] = excl; gcur[idx] = excl;
      if ((idx & 63) == 0) ccur[(idx >> 6)*CPAD] = excl;
    }
    carry += s[1023];
    __syncthreads();
  }
}

// pass 1a: coarse partition (74 buckets). 32768 keys/block; padded coarse cursors
__global__ __launch_bounds__(P1_TPB) void k_coarse_scatter(const u64* __restrict__ src,
     u64* __restrict__ dst, u32* __restrict__ ccur){
  __shared__ u32 h[NCOARSE];
  int tid = threadIdx.x;
  if (tid < NCOARSE) h[tid]=0;
  __syncthreads();
  size_t gi = (size_t)blockIdx.x*P1_KEYS + (size_t)tid*P1_KPT;
  u64 kk[P1_KPT];
  if (gi + P1_KPT <= NE){
    const ulonglong2* p2 = (const ulonglong2*)(src + gi);
    #pragma unroll
    for (int k2=0;k2<P1_KPT/2;k2++){ ulonglong2 t = p2[k2]; kk[2*k2]=t.x; kk[2*k2+1]=t.y; }
  } else {
    #pragma unroll
    for (int k=0;k<P1_KPT;k++) kk[k] = (gi+k < NE) ? src[gi+k] : ~0ull;
  }
  #pragma unroll
  for (int k=0;k<P1_KPT;k++){
    if (gi+k < NE) atomicAdd(&h[(u32)(kk[k] >> COARSESHIFT)], 1u);
  }
  __syncthreads();
  if (tid < NCOARSE){
    u32 c = h[tid];
    h[tid] = c ? atomicAdd(&ccur[tid*CPAD], c) : 0u;
  }
  __syncthreads();
  #pragma unroll
  for (int k=0;k<P1_KPT;k++){
    if (gi+k < NE){
      u32 b = (u32)(kk[k] >> COARSESHIFT);
      u32 p = atomicAdd(&h[b], 1u);
      dst[p] = kk[k];
    }
  }
}

// pass 1b: fine partition within each coarse region. grid = NCOARSE*FS_SUB.
__global__ __launch_bounds__(P1_TPB) void k_fine_scatter(const u64* __restrict__ src,
     u64* __restrict__ dst, const u32* __restrict__ boff, u32* __restrict__ gcur){
  __shared__ u32 h[64];
  __shared__ u32 rb[64];
  int c = blockIdx.x >> 3, sub = blockIdx.x & (FS_SUB-1);
  int tid = threadIdx.x;
  u32 startc = boff[c*64];
  u32 endc = (c == NCOARSE-1) ? (u32)NE : boff[(c+1)*64];
  u32 size = endc - startc;
  u32 shareLen = (size + FS_SUB - 1) / FS_SUB;
  u32 s0 = startc + sub*shareLen;
  u32 s1 = s0 + shareLen; if (s1 > endc) s1 = endc;
  if (s0 >= s1) return;
  for (u32 base = s0; base < s1; base += FS_CH){
    u32 lim = base + FS_CH; if (lim > s1) lim = s1;
    if (tid < 64) h[tid] = 0;
    __syncthreads();
    for (u32 i = base + tid; i < lim; i += P1_TPB)
      atomicAdd(&h[(u32)(src[i] >> BUCKSHIFT) & 63u], 1u);
    __syncthreads();
    if (tid < 64){
      u32 cc = h[tid];
      rb[tid] = cc ? atomicAdd(&gcur[c*64 + tid], cc) : 0u;
      h[tid] = 0;
    }
    __syncthreads();
    for (u32 i = base + tid; i < lim; i += P1_TPB){
      u64 v = src[i];
      u32 f = (u32)(v >> BUCKSHIFT) & 63u;
      u32 p = rb[f] + atomicAdd(&h[f], 1u);
      dst[p] = v;
    }
    __syncthreads();
  }
}

// pass 2: full in-LDS sort of one bucket (IN-PLACE). Size-classed NK in {4,8,12,16}.
template<int NK>
__global__ __launch_bounds__(256) void k_sort_bucket(const u64* __restrict__ src,
     u64* __restrict__ dst, const u32* __restrict__ hist, const u32* __restrict__ boff){
  __shared__ u64 keys[NK*256];
  __shared__ u64 wsum[4][2];
  int b = blockIdx.x, tid = threadIdx.x;
  u32 n = hist[b];
  if (n == 0) return;
  if (NK == 4  && n > 1024) return;
  if (NK == 8  && (n <= 1024 || n > 2048)) return;
  if (NK == 12 && (n <= 2048 || n > 3072)) return;
  if (NK == 16 && n <= 3072) return;
  u32 base = boff[b];
  #pragma unroll
  for (int k=0;k<NK;k++){
    int j = k*256 + tid;
    keys[sw(j)] = (j < (int)n) ? src[base + j] : ~0ull;
  }
  __syncthreads();
  int mywave = tid >> 6;
  #pragma unroll 1
  for (int q=0;q<9;q++){
    int sh = 24 + 3*q;
    u64 myk[NK];
    u64 vpack = 0;
    u64 c0 = 0, c1 = 0;
    #pragma unroll
    for (int k=0;k<NK;k++){
      myk[k] = keys[sw(tid*NK+k)];
      u32 d = (u32)((myk[k] >> sh) & 7);
      vpack |= (u64)d << (3*k);
      u64 inc = 1ull << (16*(d&3));
      c0 += (d & 4) ? 0 : inc;
      c1 += (d & 4) ? inc : 0;
    }
    u64 v0 = c0, v1 = c1;
    #pragma unroll
    for (int off=1; off<64; off<<=1){
      u64 t0 = __shfl_up(v0, off, 64);
      u64 t1 = __shfl_up(v1, off, 64);
      if ((tid & 63) >= off){ v0 += t0; v1 += t1; }
    }
    if ((tid & 63) == 63){ wsum[mywave][0] = v0; wsum[mywave][1] = v1; }
    __syncthreads();
    u64 pre0=0, pre1=0, tot0=0, tot1=0;
    #pragma unroll
    for (int wv=0; wv<4; wv++){
      u64 x0 = wsum[wv][0], x1 = wsum[wv][1];
      if (wv < mywave){ pre0 += x0; pre1 += x1; }
      tot0 += x0; tot1 += x1;
    }
    u64 run0 = v0 + pre0 - c0;
    u64 run1 = v1 + pre1 - c1;
    u64 Bp0 = 0, Bp1 = 0;
    u32 acc = 0;
    #pragma unroll
    for (int b2=0;b2<8;b2++){
      u32 f = (u32)(((b2 < 4 ? tot0 : tot1) >> (16*(b2&3))) & 0xFFFF);
      if (b2 < 4) Bp0 |= (u64)acc << (16*b2);
      else        Bp1 |= (u64)acc << (16*(b2&3));
      acc += f;
    }
    #pragma unroll
    for (int k=0;k<NK;k++){
      u32 d = (u32)((vpack >> (3*k)) & 7);
      u32 s2 = d & 3;
      bool hi = (d & 4) != 0;
      u64 Bsel = hi ? Bp1 : Bp0;
      u64 rsel = hi ? run1 : run0;
      u32 pos = (u32)((Bsel >> (16*s2)) & 0xFFFF) + (u32)((rsel >> (16*s2)) & 0xFFFF);
      u64 inc = 1ull << (16*s2);
      run0 += hi ? 0 : inc;
      run1 += hi ? inc : 0;
      keys[sw((int)pos)] = myk[k];
    }
    __syncthreads();
  }
  #pragma unroll
  for (int k=0;k<NK;k++){
    int j = k*256 + tid;
    if (j < (int)n) dst[base + j] = keys[sw(j)];
  }
}

// streaming per-tile (head, crossHead) counts — vectorized loads
__global__ __launch_bounds__(256) void k_tilesum(const u64* __restrict__ A, u64* __restrict__ tileSums){
  __shared__ u64 s[256];
  int tid = threadIdx.x;
  int start = blockIdx.x*TILE + tid*16;
  u64 myk[16];
  if (start < NE){
    const ulonglong2* A2 = (const ulonglong2*)(A + start);
    #pragma unroll
    for (int k2=0;k2<8;k2++){ ulonglong2 t = A2[k2]; myk[2*k2]=t.x; myk[2*k2+1]=t.y; }
  } else {
    #pragma unroll
    for (int k=0;k<16;k++) myk[k]=0;
  }
  u64 prev = (start > 0 && start <= NE) ? A[start-1] : ~0ull;
  u32 th=0, tc=0;
  #pragma unroll
  for (int k=0;k<16;k++){
    int i = start + k;
    if (i < NE){
      u64 v = myk[k];
      if ((v>>CODESHIFT) != (prev>>CODESHIFT)){
        th++;
        if ((v>>IDXBITS) & 1ull) tc++;
      }
      prev = v;
    }
  }
  s[tid] = ((u64)th<<32) | (u64)tc;
  __syncthreads();
  for (int off=128; off>0; off>>=1){
    if (tid<off) s[tid]+=s[tid+off];
    __syncthreads();
  }
  if (tid==0) tileSums[blockIdx.x] = s[0];
}

// exclusive scan over tiles; tileOff[NTILES] = grand total
__global__ void k_scan_tiles(u64* __restrict__ tileSums, u64* __restrict__ tileOff){
  __shared__ u64 s[256];
  int tid = threadIdx.x;
  u64 carry=0;
  for (int start=0; start<NTILES; start+=256){
    int idx=start+tid;
    u64 x = (idx<NTILES)? tileSums[idx] : 0;
    s[tid]=x; __syncthreads();
    for (int off=1;off<256;off<<=1){
      u64 t=(tid>=off)?s[tid-off]:0;
      __syncthreads();
      s[tid]+=t;
      __syncthreads();
    }
    u64 incl=s[tid], tot=s[255];
    if (idx<NTILES) tileOff[idx] = carry + incl - x;
    carry += tot;
    __syncthreads();
  }
  if (tid==0) tileOff[NTILES] = carry;
}

// streaming pass: crossing flags + staged pairs + dense codes[m].
// popcount-indexed positions; PADDED global cursors (one per 64B line).
__global__ __launch_bounds__(256) void k_emit_light(const u64* __restrict__ A,
     const u64* __restrict__ tileOff, u64* __restrict__ pairs, u32* __restrict__ cursors,
     u64* __restrict__ codes, float* __restrict__ crossing_out){
  __shared__ u64 wsum[4];
  __shared__ u32 cnt[NBUCK], lcur[NBUCK];
  __shared__ u32 lofs[NBUCK+1];
  __shared__ u32 gbase[NBUCK];
  __shared__ u64 stage[STAGECAP];
  int tid=threadIdx.x, blk=blockIdx.x;
  int lane = tid & 63, wv = tid >> 6;
  int start = blk*TILE + tid*16;
  if (tid < NBUCK){ cnt[tid]=0; lcur[tid]=0; }
  u64 myk[16];
  if (start < NE){
    const ulonglong2* A2 = (const ulonglong2*)(A + start);
    #pragma unroll
    for (int k2=0;k2<8;k2++){ ulonglong2 t = A2[k2]; myk[2*k2]=t.x; myk[2*k2+1]=t.y; }
  } else {
    #pragma unroll
    for (int k=0;k<16;k++) myk[k]=0;
  }
  u64 prev = (start > 0 && start <= NE) ? A[start-1] : ~0ull;
  u32 headm=0, crossm=0;
  #pragma unroll
  for (int k=0;k<16;k++){
    int i = start + k;
    if (i<NE){
      u64 v = myk[k];
      if ((v>>CODESHIFT) != (prev>>CODESHIFT)) headm |= 1u<<k;
      if ((v>>IDXBITS) & 1ull) crossm |= 1u<<k;
      prev = v;
    }
  }
  __syncthreads();   // cnt/lcur zeroed
  #pragma unroll
  for (int k=0;k<16;k++){
    if ((start+k) < NE && ((crossm>>k)&1u))
      atomicAdd(&cnt[((u32)myk[k] & IDXMASK)>>BSHIFT], 1u);
  }
  u32 th = __popc(headm), tc = __popc(headm & crossm);
  u64 x = ((u64)th<<32)|(u64)tc;
  u64 v = x;
  #pragma unroll
  for (int off=1; off<64; off<<=1){
    u64 t = __shfl_up(v, off, 64);
    if (lane >= off) v += t;
  }
  if (lane == 63) wsum[wv] = v;
  __syncthreads();
  u64 pre = 0;
  #pragma unroll
  for (int w2=0; w2<4; w2++){ u64 s2 = wsum[w2]; if (w2 < wv) pre += s2; }
  u64 excl = v - x + pre;
  if (tid < 64){
    u32 a0 = (2*tid   < NBUCK) ? cnt[2*tid]   : 0;
    u32 a1 = (2*tid+1 < NBUCK) ? cnt[2*tid+1] : 0;
    u32 sp = a0 + a1;
    u32 sv = sp;
    #pragma unroll
    for (int off=1; off<64; off<<=1){
      u32 t = __shfl_up(sv, off, 64);
      if (lane >= off) sv += t;
    }
    u32 basex = sv - sp;
    if (2*tid   < NBUCK) lofs[2*tid]   = basex;
    if (2*tid+1 < NBUCK) lofs[2*tid+1] = basex + a0;
    if (tid == 63) lofs[NBUCK] = sv;
  }
  if (tid < NBUCK) gbase[tid] = atomicAdd(&cursors[tid*CPAD], cnt[tid]);
  __syncthreads();
  bool use_stage = (lofs[NBUCK] <= STAGECAP);
  u64 baseOff = tileOff[blk] + excl;
  u32 Hbase = (u32)(baseOff>>32);
  u32 Cbase = (u32)(baseOff & 0xFFFFFFFFull);
  u32 hc = headm & crossm;
  #pragma unroll
  for (int k=0;k<16;k++){
    int i = start+k;
    if (i>=NE) break;
    u32 incl = (2u<<k)-1u;
    bool head  = (headm>>k)&1u;
    bool cross = (crossm>>k)&1u;
    u32 Hk = Hbase + __popc(headm & incl);
    u32 Ck = Cbase + __popc(hc & incl);
    if (cross){
      int m = (int)Ck-1;
      u32 orig = (u32)myk[k] & IDXMASK;
      u32 b = orig>>BSHIFT;
      u32 r = atomicAdd(&lcur[b], 1u);
      u64 pr = ((u64)orig<<32) | (u64)(u32)m;
      if (use_stage) stage[lofs[b] + r] = pr;
      else           pairs[(size_t)b*BSZ + gbase[b] + r] = pr;
    }
    if (head){
      crossing_out[Hk-1] = cross ? 1.f : 0.f;
      if (cross) codes[Ck-1] = myk[k]>>CODESHIFT;
    }
  }
  __syncthreads();
  if (use_stage){
    int ncross = (int)lofs[NBUCK];
    for (int j = tid; j < ncross; j += 256){
      u64 pr = stage[j];
      u32 b = (u32)(pr>>32) >> BSHIFT;
      pairs[(size_t)b*BSZ + gbase[b] + (u32)(j - (int)lofs[b])] = pr;
    }
  }
}

// gather-only verts pass; 40KB dummy LDS caps occupancy so psd stays L2-resident
__global__ __launch_bounds__(256) void k_verts(const u64* __restrict__ codes,
     const float4* __restrict__ psd, const u64* __restrict__ totptr, float* __restrict__ verts){
  __shared__ u64 dummy[5120];
  u32 ncross = (u32)(totptr[0] & 0xFFFFFFFFull);
  u32 stride = gridDim.x * blockDim.x;
  for (u32 i = blockIdx.x*blockDim.x + threadIdx.x; i < ncross; i += stride){
    u64 code = codes[i];
    u32 u0 = (u32)(code >> 19), u1 = (u32)(code & 0x7FFFFull);
    float4 a = psd[u0], b = psd[u1];
    float denom = a.w - b.w;
    float w0 = (-b.w)/denom, w1 = a.w/denom;
    verts[3*i+0] = a.x*w0 + b.x*w1;
    verts[3*i+1] = a.y*w0 + b.y*w1;
    verts[3*i+2] = a.z*w0 + b.z*w1;
  }
  if ((int)ncross < -1){ dummy[threadIdx.x] = codes[0]; verts[0] = (float)dummy[255]; }
}

// zero-fill tails: verts[3*ncross .. 21.6M) (incl. dead codes region) and cross[nuniq .. 7.2M)
__global__ void k_tailzero(const u64* __restrict__ totptr,
                           float* __restrict__ verts, float* __restrict__ cross){
  u64 tot = totptr[0];
  u32 nuniq  = (u32)(tot>>32);
  u32 ncross = (u32)(tot & 0xFFFFFFFFull);
  u32 vstart = 3u*ncross;
  u32 vlen = 21600000u - vstart;
  u32 clen = 7200000u - nuniq;
  u32 stride = gridDim.x * blockDim.x;
  for (u32 i = blockIdx.x*blockDim.x + threadIdx.x; i < vlen; i += stride)
    verts[vstart + i] = 0.f;
  for (u32 i = blockIdx.x*blockDim.x + threadIdx.x; i < clen; i += stride)
    cross[nuniq + i] = 0.f;
}

__global__ void k_map_scatter(const u64* __restrict__ pairs, const u32* __restrict__ cursors,
                              float* __restrict__ mapF){
  int b = blockIdx.x / BPB, sub = blockIdx.x % BPB;
  u32 n = cursors[b*CPAD];
  const u64* p = pairs + (size_t)b*BSZ;
  for (u32 i = (u32)(sub*256 + threadIdx.x); i < n; i += BPB*256){
    u64 v = p[i];
    mapF[(u32)(v>>32)] = (float)(int)(u32)v;
  }
}

// k_faces: triangle-table entries reference only CROSSING edges, always written by map_scatter
__global__ void k_faces(const float* __restrict__ occF, float* faceRegion, float* __restrict__ numt){
  int t = blockIdx.x*blockDim.x + threadIdx.x;
  if (t>=NTET) return;
  int occ = (int)occF[t];
  int ntri = c_numtri[occ];
  float em[6];
  #pragma unroll
  for (int j=0;j<6;j++) em[j] = faceRegion[t*6+j];
  float f[6];
  #pragma unroll
  for (int j=0;j<6;j++){
    int tri = c_tritab[occ][j];
    f[j] = ((j/3) < ntri) ? em[tri] : -1.f;
  }
  #pragma unroll
  for (int j=0;j<6;j++) faceRegion[t*6+j] = f[j];
  numt[t] = (float)ntri;
}

extern "C" void kernel_launch(void* const* d_in, const int* in_sizes, int n_in,
                              void* d_out, int out_size, void* d_ws, size_t ws_size,
                              hipStream_t stream) {
  const float* pos = (const float*)d_in[0];
  const float* sdf = (const float*)d_in[1];
  const int*   tet = (const int*)d_in[2];
  float* out = (float*)d_out;

  // ws layout
  char* w = (char*)d_ws;
  u64* bufA     = (u64*)w;                        // 57,600,000
  u32* hist     = (u32*)(w + 57600000);           // 18,752
  u32* boff     = (u32*)(w + 57618752);           // 18,752
  u32* gcur     = (u32*)(w + 57637504);           // 18,752
  u64* tileSums = (u64*)(w + 57656256);           // 14,064
  u64* tileOff  = (u64*)(w + 57670320);           // 14,072 (NTILES+1)
  u32* cursors  = (u32*)(w + 57684392);           // 110*16*4 = 7,040 (padded)
  u32* ccur     = (u32*)(w + 57691432);           // 74*16*4 = 4,736 (padded)
  float4* psd   = (float4*)(w + 57696176);        // 4,800,000 (16-aligned)
  u64* pairs_ws = (u64*)(w + 62496176);           // 57,600,000 -> ends 120,096,176
  u32* histBlk  = (u32*)pairs_ws;                 // 512*4688*4 (pack-time only)

  u64* bufB  = (u64*)d_out;                       // coarse-partitioned keys (bytes 0..57.6MB)
  u64* codes = (u64*)(out + CODES_ELEM);          // bytes 56MB..86.4MB

  k_pack<<<PK_GRID, 256, 0, stream>>>(tet, sdf, bufA, out + NUMT_OFF, histBlk);
  k_psd<<<(NVERT+255)/256, 256, 0, stream>>>(pos, sdf, psd);

  k_reduce_hist<<<(NBUCKS+255)/256, 256, 0, stream>>>(histBlk, hist);
  k_scan_buckets<<<1, 1024, 0, stream>>>(hist, boff, gcur, ccur);

  // pass 1a: coarse partition bufA -> bufB ; pass 1b: fine partition bufB -> bufA
  k_coarse_scatter<<<P1_GRID, P1_TPB, 0, stream>>>(bufA, bufB, ccur);
  k_fine_scatter<<<NCOARSE*FS_SUB, P1_TPB, 0, stream>>>(bufB, bufA, boff, gcur);

  // pass 2: in-place in-LDS sort of each fine bucket (size-classed)
  k_sort_bucket<4><<<NBUCKS, 256, 0, stream>>>(bufA, bufA, hist, boff);
  k_sort_bucket<8><<<NBUCKS, 256, 0, stream>>>(bufA, bufA, hist, boff);
  k_sort_bucket<12><<<NBUCKS, 256, 0, stream>>>(bufA, bufA, hist, boff);
  k_sort_bucket<16><<<NBUCKS, 256, 0, stream>>>(bufA, bufA, hist, boff);

  k_tilesum<<<NTILES, 256, 0, stream>>>(bufA, tileSums);
  k_scan_tiles<<<1, 256, 0, stream>>>(tileSums, tileOff);

  hipMemsetAsync(cursors, 0, NBUCK*CPAD*sizeof(u32), stream);

  k_emit_light<<<NTILES, 256, 0, stream>>>(bufA, tileOff, pairs_ws, cursors,
                                           codes, out + CROSS_OFF);

  k_verts<<<1024, 256, 0, stream>>>(codes, psd, tileOff + NTILES, out + VERTS_OFF);
  k_tailzero<<<2048, 256, 0, stream>>>(tileOff + NTILES, out + VERTS_OFF, out + CROSS_OFF);

  k_map_scatter<<<NBUCK*BPB, 256, 0, stream>>>(pairs_ws, cursors, out + FACES_OFF);
  k_faces<<<(NTET+255)/256, 256, 0, stream>>>(out + NUMT_OFF, out + FACES_OFF, out + NUMT_OFF);
}